// Round 20
// baseline (175.856 us; speedup 1.0000x reference)
//
#include <hip/hip_runtime.h>

typedef unsigned short u16;
typedef unsigned int u32;
typedef unsigned long long u64;
typedef __attribute__((ext_vector_type(8))) short s16x8;
typedef __attribute__((ext_vector_type(8))) __bf16 bf16x8;
typedef __attribute__((ext_vector_type(4))) float fx4;
typedef __attribute__((ext_vector_type(16))) float fx16;
typedef __attribute__((ext_vector_type(2))) u32 u32x2;
typedef __attribute__((ext_vector_type(4))) u32 u32x4;

// ---------- helpers ----------
__device__ __forceinline__ fx4 mfma_16x16x32(s16x8 a, s16x8 b, fx4 c) {
  return __builtin_amdgcn_mfma_f32_16x16x32_bf16(
      __builtin_bit_cast(bf16x8, a), __builtin_bit_cast(bf16x8, b), c, 0, 0, 0);
}
__device__ __forceinline__ fx16 mfma_32x32x16(s16x8 a, s16x8 b, fx16 c) {
  return __builtin_amdgcn_mfma_f32_32x32x16_bf16(
      __builtin_bit_cast(bf16x8, a), __builtin_bit_cast(bf16x8, b), c, 0, 0, 0);
}

__device__ __forceinline__ u16 f2bf(float f) {
  u32 u = __builtin_bit_cast(u32, f);
  u32 r = u + 0x7fffu + ((u >> 16) & 1u);
  return (u16)(r >> 16);
}
__device__ __forceinline__ float bf2f(u16 h) {
  u32 u = ((u32)h) << 16;
  return __builtin_bit_cast(float, u);
}

__device__ __forceinline__ u32 cvtpk(float lo, float hi) {
  u32 r;
  asm("v_cvt_pk_bf16_f32 %0, %1, %2" : "=v"(r) : "v"(lo), "v"(hi));
  return r;
}

__device__ __forceinline__ float max3f(float a, float b, float c) {
  float r;
  asm("v_max3_f32 %0, %1, %2, %3" : "=v"(r) : "v"(a), "v"(b), "v"(c));
  return r;
}

__device__ __forceinline__ void plswap(u32& x, u32& y) {
  typedef __attribute__((ext_vector_type(2))) unsigned int uix2;
  uix2 r = __builtin_amdgcn_permlane32_swap(x, y, false, false);
  x = r[0];
  y = r[1];
}

__device__ __forceinline__ float xhalf_max(float v) {
  u32 a = __builtin_bit_cast(u32, v), b = a;
  plswap(a, b);
  return fmaxf(__builtin_bit_cast(float, a), __builtin_bit_cast(float, b));
}
__device__ __forceinline__ float xhalf_sum(float v) {
  u32 a = __builtin_bit_cast(u32, v), b = a;
  plswap(a, b);
  return __builtin_bit_cast(float, a) + __builtin_bit_cast(float, b);
}

__device__ __forceinline__ void gload16(const void* g, void* l) {
  __builtin_amdgcn_global_load_lds(
      (const __attribute__((address_space(1))) u32*)g,
      (__attribute__((address_space(3))) u32*)l, 16, 0, 0);
}

// ---------- constants ----------
#define B_ 2
#define T_ 2048
#define C_ 1024
#define H_ 16
#define HD_ 64
#define BH_ 32
#define M_ 4096   // B*T
// (1/sqrt(64)) * log2(e), folded into Q at GEMM1 epilogue (fused RoPE)
#define CF_ 0.18033688011112042f

// ---------- fused prep ----------
__global__ __launch_bounds__(256) void prep_k(
    const float* __restrict__ x, const float* __restrict__ wa,
    const float* __restrict__ wp, u16* __restrict__ xb, u16* __restrict__ waT,
    u16* __restrict__ wpT, float* __restrict__ ct, float* __restrict__ st) {
  __shared__ u16 T_s[64 * 72];
  int b = blockIdx.x, tid = threadIdx.x;
  if (b < 2048) {
    int id = b * 256 + tid;
    const fx4* p = (const fx4*)(x + (u64)id * 8);
    fx4 v0 = p[0], v1 = p[1];
    s16x8 r;
#pragma unroll
    for (int j = 0; j < 4; ++j) {
      r[j] = (short)f2bf(v0[j]);
      r[4 + j] = (short)f2bf(v1[j]);
    }
    *((s16x8*)xb + id) = r;
  } else if (b < 3072) {
    const float* W;
    u16* WT;
    int Ncols, bx, by;
    if (b < 2816) {
      int i = b - 2048;
      W = wa; WT = waT; Ncols = 3072; bx = i % 48; by = i / 48;
    } else {
      int i = b - 2816;
      W = wp; WT = wpT; Ncols = 1024; bx = i % 16; by = i / 16;
    }
    int c0 = bx * 64, r0 = by * 64;
#pragma unroll
    for (int it = 0; it < 4; ++it) {
      int idx = it * 256 + tid;
      int r = idx >> 4, c4 = (idx & 15) * 4;
      fx4 v = *(const fx4*)(W + (u64)(r0 + r) * Ncols + c0 + c4);
#pragma unroll
      for (int j = 0; j < 4; ++j) T_s[(c4 + j) * 72 + r] = f2bf(v[j]);
    }
    __syncthreads();
#pragma unroll
    for (int it = 0; it < 2; ++it) {
      int idx = it * 256 + tid;
      int rc = idx >> 3, c8 = (idx & 7) * 8;
      s16x8 v = *(const s16x8*)(T_s + rc * 72 + c8);
      *(s16x8*)(WT + (u64)(c0 + rc) * 1024 + r0 + c8) = v;
    }
  } else {
    int id = (b - 3072) * 256 + tid;
    int t = id >> 5, i = id & 31;
    float f = exp2f(-(float)i * (13.287712379549449f / 32.0f));
    float a = (float)t * f;
    float s, c;
    sincosf(a, &s, &c);
    ct[id] = c;
    st[id] = s;
  }
}

// ---------- GEMM1: A[M][K] bf16 @ B[N][K]^T bf16, 128x128 tile, BK=32,
// ring-3 LDS pipeline (r10/r17-verified best), fused RoPE epilogue,
// scatter to blocked Qp/Kp [bh][8][T][8] (Q scaled by CF_), Vp [bh][T/8][64][8].
__global__ __launch_bounds__(256, 3) void gemm1_k(
    const u16* __restrict__ A, const u16* __restrict__ B,
    u16* __restrict__ Qo, u16* __restrict__ Ko, u16* __restrict__ Vo,
    const float* __restrict__ ct, const float* __restrict__ st,
    int M, int N, int K) {
  __shared__ u16 AsS[3][128 * 32];
  __shared__ u16 BsS[3][128 * 32];
  int tid = threadIdx.x, lane = tid & 63, w = tid >> 6;
  int wm = w >> 1, wn = w & 1, l15 = lane & 15, l4 = lane >> 4;
  int nwg = gridDim.x * gridDim.y;
  int id = blockIdx.y * gridDim.x + blockIdx.x;
  int qq = nwg >> 3;
  id = (id & 7) * qq + (id >> 3);
  int m0 = (id / gridDim.x) * 128, n0 = (id % gridDim.x) * 128;
  fx4 acc[4][4] = {};

  const u16* asrc[2];
  const u16* bsrc[2];
#pragma unroll
  for (int g = 0; g < 2; ++g) {
    int idx = g * 256 + tid;
    int row = idx >> 2, slot = (idx & 3) ^ (row & 3);
    asrc[g] = A + (u64)(m0 + row) * K + slot * 8;
    bsrc[g] = B + (u64)(n0 + row) * K + slot * 8;
  }

#define GSTAGE(S, KOFF)                                                      \
  do {                                                                       \
    _Pragma("unroll")                                                        \
    for (int g_ = 0; g_ < 2; ++g_) {                                         \
      gload16(asrc[g_] + (KOFF), (char*)AsS[S] + g_ * 4096 + tid * 16);      \
      gload16(bsrc[g_] + (KOFF), (char*)BsS[S] + g_ * 4096 + tid * 16);      \
    }                                                                        \
  } while (0)

#define GCOMP(S)                                                             \
  do {                                                                       \
    s16x8 a_[4], b_[4];                                                      \
    _Pragma("unroll")                                                        \
    for (int mi_ = 0; mi_ < 4; ++mi_) {                                      \
      int r_ = wm * 64 + mi_ * 16 + l15;                                     \
      a_[mi_] = *(const s16x8*)((const char*)AsS[S] + r_ * 64 +              \
                                ((l4 ^ (r_ & 3)) * 16));                     \
    }                                                                        \
    _Pragma("unroll")                                                        \
    for (int ni_ = 0; ni_ < 4; ++ni_) {                                      \
      int r_ = wn * 64 + ni_ * 16 + l15;                                     \
      b_[ni_] = *(const s16x8*)((const char*)BsS[S] + r_ * 64 +              \
                                ((l4 ^ (r_ & 3)) * 16));                     \
    }                                                                        \
    _Pragma("unroll")                                                        \
    for (int mi_ = 0; mi_ < 4; ++mi_)                                        \
      _Pragma("unroll")                                                      \
      for (int ni_ = 0; ni_ < 4; ++ni_)                                      \
        acc[mi_][ni_] = mfma_16x16x32(a_[mi_], b_[ni_], acc[mi_][ni_]);      \
  } while (0)

  int NT = K >> 5;  // 32
  GSTAGE(0, 0);
  GSTAGE(1, 32);
  int s0 = 0, s1 = 1, s2 = 2;
  for (int t = 0; t < NT; ++t) {
    __builtin_amdgcn_s_barrier();
    __builtin_amdgcn_sched_barrier(0);
    if (t + 2 < NT) GSTAGE(s2, (t + 2) * 32);
    __builtin_amdgcn_sched_barrier(0);
    if (t < NT - 2)
      asm volatile("s_waitcnt vmcnt(8)" ::: "memory");
    else if (t == NT - 2)
      asm volatile("s_waitcnt vmcnt(4)" ::: "memory");
    else
      asm volatile("s_waitcnt vmcnt(0)" ::: "memory");
    __builtin_amdgcn_s_barrier();
    __builtin_amdgcn_sched_barrier(0);
    GCOMP(s0);
    int tmp = s0;
    s0 = s1;
    s1 = s2;
    s2 = tmp;
  }
#undef GSTAGE
#undef GCOMP

#pragma unroll
  for (int mi = 0; mi < 4; ++mi)
#pragma unroll
    for (int r = 0; r < 4; ++r) {
      int row = m0 + wm * 64 + mi * 16 + l4 * 4 + r;
      int b2 = row >> 11, t = row & (T_ - 1);
#pragma unroll
      for (int ni = 0; ni < 2; ++ni) {
        int col = n0 + wn * 64 + ni * 16 + l15;
        int qi = col >> 10, h = (col >> 6) & 15, d = ni * 16 + l15;  // 0..31
        float lo = acc[mi][ni][r], hi = acc[mi][ni + 2][r];
        if (qi == 2) {
          u64 vbase =
              ((((u64)(b2 * H_ + h)) * (T_ / 8) + (t >> 3)) * HD_ + d) * 8 + (t & 7);
          Vo[vbase] = f2bf(lo);
          Vo[vbase + 32 * 8] = f2bf(hi);
        } else {
          float c = ct[t * 32 + d], s = st[t * 32 + d];
          float sc = (qi == 0) ? CF_ : 1.0f;
          u16* dst = (qi == 0) ? Qo : Ko;
          u64 base = ((((u64)(b2 * H_ + h)) * 8 + (d >> 3)) * T_ + t) * 8 + (d & 7);
          dst[base] = f2bf((lo * c - hi * s) * sc);
          dst[base + (u64)4 * T_ * 8] = f2bf((hi * c + lo * s) * sc);
        }
      }
    }
}

// ---------- GEMM2: BARRIER-FREE per-wave-private LDS (r17-verified) ------
__global__ __launch_bounds__(256, 2) void gemm2_nb(
    const u16* __restrict__ A, const u16* __restrict__ B, float* __restrict__ C,
    int M, int N, int K) {
  __shared__ u16 lds[4][2][2][64 * 32];  // [wave][buf][mat][64x32] = 64KB
  int tid = threadIdx.x, lane = tid & 63, w = tid >> 6;
  int wm = w >> 1, wn = w & 1, l15 = lane & 15, l4 = lane >> 4;
  int nwg = gridDim.x * gridDim.y;
  int id = blockIdx.y * gridDim.x + blockIdx.x;
  int qq = nwg >> 3;
  id = (id & 7) * qq + (id >> 3);
  int m0 = (id / gridDim.x) * 128 + wm * 64;
  int n0 = (id % gridDim.x) * 128 + wn * 64;
  fx4 acc[4][4] = {};

  const u16* asrc[4];
  const u16* bsrc[4];
  int doff[4];
#pragma unroll
  for (int g = 0; g < 4; ++g) {
    int p = g * 64 + lane;
    int row = p >> 2, slot = (p & 3) ^ (row & 3);
    doff[g] = p * 16;
    asrc[g] = A + (u64)(m0 + row) * K + slot * 8;
    bsrc[g] = B + (u64)(n0 + row) * K + slot * 8;
  }

#define STG(BUF, KOFF)                                                       \
  do {                                                                       \
    _Pragma("unroll")                                                        \
    for (int g_ = 0; g_ < 4; ++g_) {                                         \
      gload16(asrc[g_] + (KOFF), (char*)lds[w][BUF][0] + doff[g_]);          \
      gload16(bsrc[g_] + (KOFF), (char*)lds[w][BUF][1] + doff[g_]);          \
    }                                                                        \
  } while (0)

#define CMP(BUF)                                                             \
  do {                                                                       \
    s16x8 a_[4], b_[4];                                                      \
    _Pragma("unroll")                                                        \
    for (int mi_ = 0; mi_ < 4; ++mi_) {                                      \
      int r_ = mi_ * 16 + l15;                                               \
      a_[mi_] = *(const s16x8*)((const char*)lds[w][BUF][0] + r_ * 64 +      \
                                ((l4 ^ (r_ & 3)) * 16));                     \
    }                                                                        \
    _Pragma("unroll")                                                        \
    for (int ni_ = 0; ni_ < 4; ++ni_) {                                      \
      int r_ = ni_ * 16 + l15;                                               \
      b_[ni_] = *(const s16x8*)((const char*)lds[w][BUF][1] + r_ * 64 +      \
                                ((l4 ^ (r_ & 3)) * 16));                     \
    }                                                                        \
    _Pragma("unroll")                                                        \
    for (int mi_ = 0; mi_ < 4; ++mi_)                                        \
      _Pragma("unroll")                                                      \
      for (int ni_ = 0; ni_ < 4; ++ni_)                                      \
        acc[mi_][ni_] = mfma_16x16x32(a_[mi_], b_[ni_], acc[mi_][ni_]);      \
  } while (0)

  int NT = K >> 5;  // 32
  STG(0, 0);
  for (int t = 0; t < NT; ++t) {
    __builtin_amdgcn_sched_barrier(0);
    if (t + 1 < NT) {
      STG((t + 1) & 1, (t + 1) * 32);
      asm volatile("s_waitcnt vmcnt(8)" ::: "memory");
    } else {
      asm volatile("s_waitcnt vmcnt(0)" ::: "memory");
    }
    __builtin_amdgcn_sched_barrier(0);
    CMP(t & 1);
  }
#undef STG
#undef CMP

#pragma unroll
  for (int mi = 0; mi < 4; ++mi)
#pragma unroll
    for (int ni = 0; ni < 4; ++ni)
#pragma unroll
      for (int r = 0; r < 4; ++r) {
        u64 row = (u64)(m0 + mi * 16 + l4 * 4 + r);
        int col = n0 + ni * 16 + l15;
        C[row * N + col] = acc[mi][ni][r];
      }
}

// ---------- flash attention: swapped-QK^T, 4 waves/block on ONE q-tile,
// each wave owns a KV quarter; merge through LDS at block end.
// VALU trims: per-half l partial (one xhalf_sum at end), cross-half max
// gated behind the per-half __all check (equivalent condition).
#define LOADK(KC, KVI)                                                 \
  do {                                                                 \
    _Pragma("unroll")                                                  \
    for (int ks_ = 0; ks_ < 4; ++ks_)                                  \
      KC[ks_] = *(const s16x8*)(kp[ks_] + (u64)(KVI) * 256);           \
  } while (0)

#define LOADV(VC, KVI)                                                 \
  do {                                                                 \
    const u16* vk_ = vpb + (u64)(KVI) * 2048;                          \
    VC[0] = *(const s16x8*)(vk_);                                      \
    VC[1] = *(const s16x8*)(vk_ + 256);                                \
    VC[2] = *(const s16x8*)(vk_ + 1024);                               \
    VC[3] = *(const s16x8*)(vk_ + 1280);                               \
  } while (0)

#define ATTN_STEP(KC, VC, KVI)                                                \
  do {                                                                        \
    fx16 s_ = {};                                                             \
    __builtin_amdgcn_s_setprio(1);                                            \
    _Pragma("unroll")                                                         \
    for (int ks_ = 0; ks_ < 4; ++ks_)                                         \
      s_ = mfma_32x32x16(KC[ks_], qf[ks_], s_);                               \
    __builtin_amdgcn_s_setprio(0);                                            \
    if ((KVI) == jt) {                                                        \
      _Pragma("unroll")                                                       \
      for (int r_ = 0; r_ < 16; ++r_) {                                       \
        int cr_ = (r_ & 3) + 8 * (r_ >> 2) + 4 * h;                           \
        s_[r_] = (cr_ > ql) ? -1e30f : s_[r_];                                \
      }                                                                       \
    }                                                                         \
    float u0_ = max3f(s_[0], s_[1], s_[2]);                                   \
    float u1_ = max3f(s_[3], s_[4], s_[5]);                                   \
    float u2_ = max3f(s_[6], s_[7], s_[8]);                                   \
    float u3_ = max3f(s_[9], s_[10], s_[11]);                                 \
    float u4_ = max3f(s_[12], s_[13], s_[14]);                                \
    float v0_ = max3f(u0_, u1_, s_[15]);                                      \
    float v1_ = max3f(u2_, u3_, u4_);                                         \
    float halfmax_ = fmaxf(v0_, v1_);                                         \
    if (!__all(halfmax_ <= m + 8.f)) {                                        \
      float rowmax_ = xhalf_max(halfmax_);                                    \
      float mnew_ = fmaxf(m, rowmax_);                                        \
      float corr_ = exp2f(m - mnew_);                                         \
      l *= corr_;                                                             \
      oL *= corr_;                                                            \
      oH *= corr_;                                                            \
      m = mnew_;                                                              \
    }                                                                         \
    float p_[16];                                                             \
    _Pragma("unroll")                                                         \
    for (int r_ = 0; r_ < 16; ++r_) p_[r_] = exp2f(s_[r_] - m);               \
    float a0_ = (p_[0] + p_[8]) + (p_[1] + p_[9]);                            \
    float a1_ = (p_[2] + p_[10]) + (p_[3] + p_[11]);                          \
    float a2_ = (p_[4] + p_[12]) + (p_[5] + p_[13]);                          \
    float a3_ = (p_[6] + p_[14]) + (p_[7] + p_[15]);                          \
    l += (a0_ + a1_) + (a2_ + a3_);  /* per-half partial; combined at end */  \
    u32 x0_ = cvtpk(p_[0], p_[1]), x1_ = cvtpk(p_[2], p_[3]);                 \
    u32 y0_ = cvtpk(p_[4], p_[5]), y1_ = cvtpk(p_[6], p_[7]);                 \
    plswap(x0_, y0_);                                                         \
    plswap(x1_, y1_);                                                         \
    u32x4 f0w_ = {x0_, x1_, y0_, y1_};                                        \
    u32 x2_ = cvtpk(p_[8], p_[9]), x3_ = cvtpk(p_[10], p_[11]);               \
    u32 y2_ = cvtpk(p_[12], p_[13]), y3_ = cvtpk(p_[14], p_[15]);             \
    plswap(x2_, y2_);                                                         \
    plswap(x3_, y3_);                                                         \
    u32x4 f1w_ = {x2_, x3_, y2_, y3_};                                        \
    s16x8 pf0_ = __builtin_bit_cast(s16x8, f0w_);                             \
    s16x8 pf1_ = __builtin_bit_cast(s16x8, f1w_);                             \
    __builtin_amdgcn_s_setprio(1);                                            \
    oL = mfma_32x32x16(VC[0], pf0_, oL);                                      \
    oH = mfma_32x32x16(VC[1], pf0_, oH);                                      \
    oL = mfma_32x32x16(VC[2], pf1_, oL);                                      \
    oH = mfma_32x32x16(VC[3], pf1_, oH);                                      \
    __builtin_amdgcn_s_setprio(0);                                            \
  } while (0)

#define OSTRIDE 68  // f32 row stride in LDS (bank-friendly, 16B-aligned)

__global__ __launch_bounds__(256, 4) void attn_fwd_k(
    const u16* __restrict__ Qp, const u16* __restrict__ Kp,
    const u16* __restrict__ Vp, u16* __restrict__ Y) {
  __shared__ float Ob[4 * 32 * OSTRIDE];   // 34816 B
  __shared__ float Ml[4 * 32 * 2];         // 1024 B
  int tid = threadIdx.x, lane = tid & 63, w = tid >> 6;
  int ql = lane & 31, h = lane >> 5;
  int bh = blockIdx.x & 31;
  int jt = 63 - (blockIdx.x >> 5);   // long tiles first
  int q0 = jt * 32;
  int b2 = bh >> 4, head = bh & 15;
  int n = jt + 1;
  int lo = (w * n) >> 2, hi = ((w + 1) * n) >> 2;  // this wave's KV range

  s16x8 qf[4];
#pragma unroll
  for (int ks = 0; ks < 4; ++ks)
    qf[ks] = *(const s16x8*)(Qp + (((u64)bh * 8 + ks * 2 + h) * T_ + q0 + ql) * 8);

  const u16* kp[4];
#pragma unroll
  for (int ks = 0; ks < 4; ++ks)
    kp[ks] = Kp + (((u64)bh * 8 + ks * 2 + h) * T_ + ql) * 8;
  const u16* vpb = Vp + (((u64)bh * (T_ / 8) + h) * HD_ + ql) * 8;

  fx16 oL = {}, oH = {};
  float m = -1e30f, l = 0.f;

  if (lo < hi) {
    s16x8 kA[4], vA[4], kB[4], vB[4];
    LOADK(kA, lo);
    LOADV(vA, lo);
    int kv = lo;
    for (; kv + 1 < hi; kv += 2) {
      LOADK(kB, kv + 1);
      LOADV(vB, kv + 1);
      ATTN_STEP(kA, vA, kv);
      if (kv + 2 < hi) {
        LOADK(kA, kv + 2);
        LOADV(vA, kv + 2);
      }
      ATTN_STEP(kB, vB, kv + 1);
    }
    if (kv < hi) ATTN_STEP(kA, vA, kv);
  }

  // combine per-half l partials once
  l = xhalf_sum(l);

  {
    float* ob = Ob + (w * 32 + ql) * OSTRIDE;
#pragma unroll
    for (int g = 0; g < 4; ++g) {
      fx4 a = {oL[4 * g], oL[4 * g + 1], oL[4 * g + 2], oL[4 * g + 3]};
      *(fx4*)(ob + 8 * g + 4 * h) = a;
      fx4 b = {oH[4 * g], oH[4 * g + 1], oH[4 * g + 2], oH[4 * g + 3]};
      *(fx4*)(ob + 32 + 8 * g + 4 * h) = b;
    }
    if (h == 0) {
      Ml[(w * 32 + ql) * 2] = m;
      Ml[(w * 32 + ql) * 2 + 1] = l;
    }
  }
  __syncthreads();

  {
    int q = tid >> 3, db = tid & 7;
    float mm0 = Ml[(0 * 32 + q) * 2], ll0 = Ml[(0 * 32 + q) * 2 + 1];
    float mm1 = Ml[(1 * 32 + q) * 2], ll1 = Ml[(1 * 32 + q) * 2 + 1];
    float mm2 = Ml[(2 * 32 + q) * 2], ll2 = Ml[(2 * 32 + q) * 2 + 1];
    float mm3 = Ml[(3 * 32 + q) * 2], ll3 = Ml[(3 * 32 + q) * 2 + 1];
    float mo = fmaxf(fmaxf(mm0, mm1), fmaxf(mm2, mm3));
    float w0 = exp2f(mm0 - mo), w1 = exp2f(mm1 - mo);
    float w2 = exp2f(mm2 - mo), w3 = exp2f(mm3 - mo);
    float rl = 1.0f / (ll0 * w0 + ll1 * w1 + ll2 * w2 + ll3 * w3);
    w0 *= rl; w1 *= rl; w2 *= rl; w3 *= rl;
    const float* ob = Ob + q * OSTRIDE + db * 8;
    fx4 aa = {}, bb = {};
#pragma unroll
    for (int i = 0; i < 4; ++i) {
      float wi = (i == 0) ? w0 : (i == 1) ? w1 : (i == 2) ? w2 : w3;
      fx4 pa = *(const fx4*)(ob + i * 32 * OSTRIDE);
      fx4 pb = *(const fx4*)(ob + i * 32 * OSTRIDE + 4);
      aa += wi * pa;
      bb += wi * pb;
    }
    u32x4 ow;
    ow[0] = cvtpk(aa[0], aa[1]);
    ow[1] = cvtpk(aa[2], aa[3]);
    ow[2] = cvtpk(bb[0], bb[1]);
    ow[3] = cvtpk(bb[2], bb[3]);
    int t = q0 + q;
    *(u32x4*)(Y + ((u64)(b2 * T_ + t)) * C_ + head * HD_ + db * 8) = ow;
  }
}

// ---------- launcher ----------
extern "C" void kernel_launch(void* const* d_in, const int* in_sizes, int n_in,
                              void* d_out, int out_size, void* d_ws, size_t ws_size,
                              hipStream_t stream) {
  (void)in_sizes; (void)n_in; (void)out_size; (void)ws_size;
  const float* x = (const float*)d_in[0];
  const float* w_attn = (const float*)d_in[1];
  const float* w_proj = (const float*)d_in[2];
  float* out = (float*)d_out;

  u16* xb = (u16*)d_ws;                       // [4096][1024] bf16 (reused as Y)
  u16* waT = xb + (u64)M_ * C_;               // [3072][1024]
  u16* wpT = waT + (u64)3 * C_ * C_;          // [1024][1024]
  u16* Qp = wpT + (u64)C_ * C_;               // [32][8][2048][8]
  u16* Kp = Qp + (u64)BH_ * T_ * HD_;
  u16* Vp = Kp + (u64)BH_ * T_ * HD_;         // [32][256][64][8]
  float* ct = (float*)(Vp + (u64)BH_ * T_ * HD_);
  float* st = ct + T_ * 32;
  u16* yb = xb;                               // reuse xb after GEMM1

  prep_k<<<3328, 256, 0, stream>>>(x, w_attn, w_proj, xb, waT, wpT, ct, st);

  gemm1_k<<<dim3(24, 32), 256, 0, stream>>>(xb, waT, Qp, Kp, Vp,
                                            ct, st, M_, 3 * C_, C_);

  attn_fwd_k<<<2048, 256, 0, stream>>>(Qp, Kp, Vp, yb);

  gemm2_nb<<<dim3(8, 32), 256, 0, stream>>>(yb, wpT, out, M_, C_, C_);
}

// Round 21
// 103.986 us; speedup vs baseline: 1.6912x; 1.6912x over previous
//
#include <hip/hip_runtime.h>

typedef unsigned short u16;
typedef unsigned int u32;
typedef unsigned long long u64;
typedef __attribute__((ext_vector_type(8))) short s16x8;
typedef __attribute__((ext_vector_type(8))) __bf16 bf16x8;
typedef __attribute__((ext_vector_type(4))) float fx4;
typedef __attribute__((ext_vector_type(16))) float fx16;
typedef __attribute__((ext_vector_type(2))) u32 u32x2;
typedef __attribute__((ext_vector_type(4))) u32 u32x4;

// ---------- helpers ----------
__device__ __forceinline__ fx4 mfma_16x16x32(s16x8 a, s16x8 b, fx4 c) {
  return __builtin_amdgcn_mfma_f32_16x16x32_bf16(
      __builtin_bit_cast(bf16x8, a), __builtin_bit_cast(bf16x8, b), c, 0, 0, 0);
}
__device__ __forceinline__ fx16 mfma_32x32x16(s16x8 a, s16x8 b, fx16 c) {
  return __builtin_amdgcn_mfma_f32_32x32x16_bf16(
      __builtin_bit_cast(bf16x8, a), __builtin_bit_cast(bf16x8, b), c, 0, 0, 0);
}

__device__ __forceinline__ u16 f2bf(float f) {
  u32 u = __builtin_bit_cast(u32, f);
  u32 r = u + 0x7fffu + ((u >> 16) & 1u);
  return (u16)(r >> 16);
}
__device__ __forceinline__ float bf2f(u16 h) {
  u32 u = ((u32)h) << 16;
  return __builtin_bit_cast(float, u);
}

__device__ __forceinline__ u32 cvtpk(float lo, float hi) {
  u32 r;
  asm("v_cvt_pk_bf16_f32 %0, %1, %2" : "=v"(r) : "v"(lo), "v"(hi));
  return r;
}

__device__ __forceinline__ float max3f(float a, float b, float c) {
  float r;
  asm("v_max3_f32 %0, %1, %2, %3" : "=v"(r) : "v"(a), "v"(b), "v"(c));
  return r;
}

__device__ __forceinline__ void plswap(u32& x, u32& y) {
  typedef __attribute__((ext_vector_type(2))) unsigned int uix2;
  uix2 r = __builtin_amdgcn_permlane32_swap(x, y, false, false);
  x = r[0];
  y = r[1];
}

__device__ __forceinline__ float xhalf_max(float v) {
  u32 a = __builtin_bit_cast(u32, v), b = a;
  plswap(a, b);
  return fmaxf(__builtin_bit_cast(float, a), __builtin_bit_cast(float, b));
}
__device__ __forceinline__ float xhalf_sum(float v) {
  u32 a = __builtin_bit_cast(u32, v), b = a;
  plswap(a, b);
  return __builtin_bit_cast(float, a) + __builtin_bit_cast(float, b);
}

__device__ __forceinline__ void gload16(const void* g, void* l) {
  __builtin_amdgcn_global_load_lds(
      (const __attribute__((address_space(1))) u32*)g,
      (__attribute__((address_space(3))) u32*)l, 16, 0, 0);
}

// ---------- constants ----------
#define B_ 2
#define T_ 2048
#define C_ 1024
#define H_ 16
#define HD_ 64
#define BH_ 32
#define M_ 4096   // B*T
// (1/sqrt(64)) * log2(e), folded into Q at GEMM1 epilogue (fused RoPE)
#define CF_ 0.18033688011112042f

// ---------- fused prep ----------
__global__ __launch_bounds__(256) void prep_k(
    const float* __restrict__ x, const float* __restrict__ wa,
    const float* __restrict__ wp, u16* __restrict__ xb, u16* __restrict__ waT,
    u16* __restrict__ wpT, float* __restrict__ ct, float* __restrict__ st) {
  __shared__ u16 T_s[64 * 72];
  int b = blockIdx.x, tid = threadIdx.x;
  if (b < 2048) {
    int id = b * 256 + tid;
    const fx4* p = (const fx4*)(x + (u64)id * 8);
    fx4 v0 = p[0], v1 = p[1];
    s16x8 r;
#pragma unroll
    for (int j = 0; j < 4; ++j) {
      r[j] = (short)f2bf(v0[j]);
      r[4 + j] = (short)f2bf(v1[j]);
    }
    *((s16x8*)xb + id) = r;
  } else if (b < 3072) {
    const float* W;
    u16* WT;
    int Ncols, bx, by;
    if (b < 2816) {
      int i = b - 2048;
      W = wa; WT = waT; Ncols = 3072; bx = i % 48; by = i / 48;
    } else {
      int i = b - 2816;
      W = wp; WT = wpT; Ncols = 1024; bx = i % 16; by = i / 16;
    }
    int c0 = bx * 64, r0 = by * 64;
#pragma unroll
    for (int it = 0; it < 4; ++it) {
      int idx = it * 256 + tid;
      int r = idx >> 4, c4 = (idx & 15) * 4;
      fx4 v = *(const fx4*)(W + (u64)(r0 + r) * Ncols + c0 + c4);
#pragma unroll
      for (int j = 0; j < 4; ++j) T_s[(c4 + j) * 72 + r] = f2bf(v[j]);
    }
    __syncthreads();
#pragma unroll
    for (int it = 0; it < 2; ++it) {
      int idx = it * 256 + tid;
      int rc = idx >> 3, c8 = (idx & 7) * 8;
      s16x8 v = *(const s16x8*)(T_s + rc * 72 + c8);
      *(s16x8*)(WT + (u64)(c0 + rc) * 1024 + r0 + c8) = v;
    }
  } else {
    int id = (b - 3072) * 256 + tid;
    int t = id >> 5, i = id & 31;
    float f = exp2f(-(float)i * (13.287712379549449f / 32.0f));
    float a = (float)t * f;
    float s, c;
    sincosf(a, &s, &c);
    ct[id] = c;
    st[id] = s;
  }
}

// ---------- GEMM1: A[M][K] bf16 @ B[N][K]^T bf16, 128x128 tile, BK=32,
// ring-3 LDS pipeline (r10/r17-verified best), fused RoPE epilogue,
// scatter to blocked Qp/Kp [bh][8][T][8] (Q scaled by CF_), Vp [bh][T/8][64][8].
__global__ __launch_bounds__(256, 3) void gemm1_k(
    const u16* __restrict__ A, const u16* __restrict__ B,
    u16* __restrict__ Qo, u16* __restrict__ Ko, u16* __restrict__ Vo,
    const float* __restrict__ ct, const float* __restrict__ st,
    int M, int N, int K) {
  __shared__ u16 AsS[3][128 * 32];
  __shared__ u16 BsS[3][128 * 32];
  int tid = threadIdx.x, lane = tid & 63, w = tid >> 6;
  int wm = w >> 1, wn = w & 1, l15 = lane & 15, l4 = lane >> 4;
  int nwg = gridDim.x * gridDim.y;
  int id = blockIdx.y * gridDim.x + blockIdx.x;
  int qq = nwg >> 3;
  id = (id & 7) * qq + (id >> 3);
  int m0 = (id / gridDim.x) * 128, n0 = (id % gridDim.x) * 128;
  fx4 acc[4][4] = {};

  const u16* asrc[2];
  const u16* bsrc[2];
#pragma unroll
  for (int g = 0; g < 2; ++g) {
    int idx = g * 256 + tid;
    int row = idx >> 2, slot = (idx & 3) ^ (row & 3);
    asrc[g] = A + (u64)(m0 + row) * K + slot * 8;
    bsrc[g] = B + (u64)(n0 + row) * K + slot * 8;
  }

#define GSTAGE(S, KOFF)                                                      \
  do {                                                                       \
    _Pragma("unroll")                                                        \
    for (int g_ = 0; g_ < 2; ++g_) {                                         \
      gload16(asrc[g_] + (KOFF), (char*)AsS[S] + g_ * 4096 + tid * 16);      \
      gload16(bsrc[g_] + (KOFF), (char*)BsS[S] + g_ * 4096 + tid * 16);      \
    }                                                                        \
  } while (0)

#define GCOMP(S)                                                             \
  do {                                                                       \
    s16x8 a_[4], b_[4];                                                      \
    _Pragma("unroll")                                                        \
    for (int mi_ = 0; mi_ < 4; ++mi_) {                                      \
      int r_ = wm * 64 + mi_ * 16 + l15;                                     \
      a_[mi_] = *(const s16x8*)((const char*)AsS[S] + r_ * 64 +              \
                                ((l4 ^ (r_ & 3)) * 16));                     \
    }                                                                        \
    _Pragma("unroll")                                                        \
    for (int ni_ = 0; ni_ < 4; ++ni_) {                                      \
      int r_ = wn * 64 + ni_ * 16 + l15;                                     \
      b_[ni_] = *(const s16x8*)((const char*)BsS[S] + r_ * 64 +              \
                                ((l4 ^ (r_ & 3)) * 16));                     \
    }                                                                        \
    _Pragma("unroll")                                                        \
    for (int mi_ = 0; mi_ < 4; ++mi_)                                        \
      _Pragma("unroll")                                                      \
      for (int ni_ = 0; ni_ < 4; ++ni_)                                      \
        acc[mi_][ni_] = mfma_16x16x32(a_[mi_], b_[ni_], acc[mi_][ni_]);      \
  } while (0)

  int NT = K >> 5;  // 32
  GSTAGE(0, 0);
  GSTAGE(1, 32);
  int s0 = 0, s1 = 1, s2 = 2;
  for (int t = 0; t < NT; ++t) {
    __builtin_amdgcn_s_barrier();
    __builtin_amdgcn_sched_barrier(0);
    if (t + 2 < NT) GSTAGE(s2, (t + 2) * 32);
    __builtin_amdgcn_sched_barrier(0);
    if (t < NT - 2)
      asm volatile("s_waitcnt vmcnt(8)" ::: "memory");
    else if (t == NT - 2)
      asm volatile("s_waitcnt vmcnt(4)" ::: "memory");
    else
      asm volatile("s_waitcnt vmcnt(0)" ::: "memory");
    __builtin_amdgcn_s_barrier();
    __builtin_amdgcn_sched_barrier(0);
    GCOMP(s0);
    int tmp = s0;
    s0 = s1;
    s1 = s2;
    s2 = tmp;
  }
#undef GSTAGE
#undef GCOMP

#pragma unroll
  for (int mi = 0; mi < 4; ++mi)
#pragma unroll
    for (int r = 0; r < 4; ++r) {
      int row = m0 + wm * 64 + mi * 16 + l4 * 4 + r;
      int b2 = row >> 11, t = row & (T_ - 1);
#pragma unroll
      for (int ni = 0; ni < 2; ++ni) {
        int col = n0 + wn * 64 + ni * 16 + l15;
        int qi = col >> 10, h = (col >> 6) & 15, d = ni * 16 + l15;  // 0..31
        float lo = acc[mi][ni][r], hi = acc[mi][ni + 2][r];
        if (qi == 2) {
          u64 vbase =
              ((((u64)(b2 * H_ + h)) * (T_ / 8) + (t >> 3)) * HD_ + d) * 8 + (t & 7);
          Vo[vbase] = f2bf(lo);
          Vo[vbase + 32 * 8] = f2bf(hi);
        } else {
          float c = ct[t * 32 + d], s = st[t * 32 + d];
          float sc = (qi == 0) ? CF_ : 1.0f;
          u16* dst = (qi == 0) ? Qo : Ko;
          u64 base = ((((u64)(b2 * H_ + h)) * 8 + (d >> 3)) * T_ + t) * 8 + (d & 7);
          dst[base] = f2bf((lo * c - hi * s) * sc);
          dst[base + (u64)4 * T_ * 8] = f2bf((hi * c + lo * s) * sc);
        }
      }
    }
}

// ---------- GEMM2: BARRIER-FREE per-wave-private LDS (r17-verified) ------
__global__ __launch_bounds__(256, 2) void gemm2_nb(
    const u16* __restrict__ A, const u16* __restrict__ B, float* __restrict__ C,
    int M, int N, int K) {
  __shared__ u16 lds[4][2][2][64 * 32];  // [wave][buf][mat][64x32] = 64KB
  int tid = threadIdx.x, lane = tid & 63, w = tid >> 6;
  int wm = w >> 1, wn = w & 1, l15 = lane & 15, l4 = lane >> 4;
  int nwg = gridDim.x * gridDim.y;
  int id = blockIdx.y * gridDim.x + blockIdx.x;
  int qq = nwg >> 3;
  id = (id & 7) * qq + (id >> 3);
  int m0 = (id / gridDim.x) * 128 + wm * 64;
  int n0 = (id % gridDim.x) * 128 + wn * 64;
  fx4 acc[4][4] = {};

  const u16* asrc[4];
  const u16* bsrc[4];
  int doff[4];
#pragma unroll
  for (int g = 0; g < 4; ++g) {
    int p = g * 64 + lane;
    int row = p >> 2, slot = (p & 3) ^ (row & 3);
    doff[g] = p * 16;
    asrc[g] = A + (u64)(m0 + row) * K + slot * 8;
    bsrc[g] = B + (u64)(n0 + row) * K + slot * 8;
  }

#define STG(BUF, KOFF)                                                       \
  do {                                                                       \
    _Pragma("unroll")                                                        \
    for (int g_ = 0; g_ < 4; ++g_) {                                         \
      gload16(asrc[g_] + (KOFF), (char*)lds[w][BUF][0] + doff[g_]);          \
      gload16(bsrc[g_] + (KOFF), (char*)lds[w][BUF][1] + doff[g_]);          \
    }                                                                        \
  } while (0)

#define CMP(BUF)                                                             \
  do {                                                                       \
    s16x8 a_[4], b_[4];                                                      \
    _Pragma("unroll")                                                        \
    for (int mi_ = 0; mi_ < 4; ++mi_) {                                      \
      int r_ = mi_ * 16 + l15;                                               \
      a_[mi_] = *(const s16x8*)((const char*)lds[w][BUF][0] + r_ * 64 +      \
                                ((l4 ^ (r_ & 3)) * 16));                     \
    }                                                                        \
    _Pragma("unroll")                                                        \
    for (int ni_ = 0; ni_ < 4; ++ni_) {                                      \
      int r_ = ni_ * 16 + l15;                                               \
      b_[ni_] = *(const s16x8*)((const char*)lds[w][BUF][1] + r_ * 64 +      \
                                ((l4 ^ (r_ & 3)) * 16));                     \
    }                                                                        \
    _Pragma("unroll")                                                        \
    for (int mi_ = 0; mi_ < 4; ++mi_)                                        \
      _Pragma("unroll")                                                      \
      for (int ni_ = 0; ni_ < 4; ++ni_)                                      \
        acc[mi_][ni_] = mfma_16x16x32(a_[mi_], b_[ni_], acc[mi_][ni_]);      \
  } while (0)

  int NT = K >> 5;  // 32
  STG(0, 0);
  for (int t = 0; t < NT; ++t) {
    __builtin_amdgcn_sched_barrier(0);
    if (t + 1 < NT) {
      STG((t + 1) & 1, (t + 1) * 32);
      asm volatile("s_waitcnt vmcnt(8)" ::: "memory");
    } else {
      asm volatile("s_waitcnt vmcnt(0)" ::: "memory");
    }
    __builtin_amdgcn_sched_barrier(0);
    CMP(t & 1);
  }
#undef STG
#undef CMP

#pragma unroll
  for (int mi = 0; mi < 4; ++mi)
#pragma unroll
    for (int ni = 0; ni < 4; ++ni)
#pragma unroll
      for (int r = 0; r < 4; ++r) {
        u64 row = (u64)(m0 + mi * 16 + l4 * 4 + r);
        int col = n0 + ni * 16 + l15;
        C[row * N + col] = acc[mi][ni][r];
      }
}

// ---------- flash attention: swapped-QK^T, 4 waves/block on ONE q-tile,
// each wave owns a KV quarter; merge through LDS at block end.
// VALU trims (kept from r20): per-half l partial (one xhalf_sum at end),
// cross-half max gated behind the per-half __all check.
#define LOADK(KC, KVI)                                                 \
  do {                                                                 \
    _Pragma("unroll")                                                  \
    for (int ks_ = 0; ks_ < 4; ++ks_)                                  \
      KC[ks_] = *(const s16x8*)(kp[ks_] + (u64)(KVI) * 256);           \
  } while (0)

#define LOADV(VC, KVI)                                                 \
  do {                                                                 \
    const u16* vk_ = vpb + (u64)(KVI) * 2048;                          \
    VC[0] = *(const s16x8*)(vk_);                                      \
    VC[1] = *(const s16x8*)(vk_ + 256);                                \
    VC[2] = *(const s16x8*)(vk_ + 1024);                               \
    VC[3] = *(const s16x8*)(vk_ + 1280);                               \
  } while (0)

#define ATTN_STEP(KC, VC, KVI)                                                \
  do {                                                                        \
    fx16 s_ = {};                                                             \
    __builtin_amdgcn_s_setprio(1);                                            \
    _Pragma("unroll")                                                         \
    for (int ks_ = 0; ks_ < 4; ++ks_)                                         \
      s_ = mfma_32x32x16(KC[ks_], qf[ks_], s_);                               \
    __builtin_amdgcn_s_setprio(0);                                            \
    if ((KVI) == jt) {                                                        \
      _Pragma("unroll")                                                       \
      for (int r_ = 0; r_ < 16; ++r_) {                                       \
        int cr_ = (r_ & 3) + 8 * (r_ >> 2) + 4 * h;                           \
        s_[r_] = (cr_ > ql) ? -1e30f : s_[r_];                                \
      }                                                                       \
    }                                                                         \
    float u0_ = max3f(s_[0], s_[1], s_[2]);                                   \
    float u1_ = max3f(s_[3], s_[4], s_[5]);                                   \
    float u2_ = max3f(s_[6], s_[7], s_[8]);                                   \
    float u3_ = max3f(s_[9], s_[10], s_[11]);                                 \
    float u4_ = max3f(s_[12], s_[13], s_[14]);                                \
    float v0_ = max3f(u0_, u1_, s_[15]);                                      \
    float v1_ = max3f(u2_, u3_, u4_);                                         \
    float halfmax_ = fmaxf(v0_, v1_);                                         \
    if (!__all(halfmax_ <= m + 8.f)) {                                        \
      float rowmax_ = xhalf_max(halfmax_);                                    \
      float mnew_ = fmaxf(m, rowmax_);                                        \
      float corr_ = exp2f(m - mnew_);                                         \
      l *= corr_;                                                             \
      oL *= corr_;                                                            \
      oH *= corr_;                                                            \
      m = mnew_;                                                              \
    }                                                                         \
    float p_[16];                                                             \
    _Pragma("unroll")                                                         \
    for (int r_ = 0; r_ < 16; ++r_) p_[r_] = exp2f(s_[r_] - m);               \
    float a0_ = (p_[0] + p_[8]) + (p_[1] + p_[9]);                            \
    float a1_ = (p_[2] + p_[10]) + (p_[3] + p_[11]);                          \
    float a2_ = (p_[4] + p_[12]) + (p_[5] + p_[13]);                          \
    float a3_ = (p_[6] + p_[14]) + (p_[7] + p_[15]);                          \
    l += (a0_ + a1_) + (a2_ + a3_);  /* per-half partial; combined at end */  \
    u32 x0_ = cvtpk(p_[0], p_[1]), x1_ = cvtpk(p_[2], p_[3]);                 \
    u32 y0_ = cvtpk(p_[4], p_[5]), y1_ = cvtpk(p_[6], p_[7]);                 \
    plswap(x0_, y0_);                                                         \
    plswap(x1_, y1_);                                                         \
    u32x4 f0w_ = {x0_, x1_, y0_, y1_};                                        \
    u32 x2_ = cvtpk(p_[8], p_[9]), x3_ = cvtpk(p_[10], p_[11]);               \
    u32 y2_ = cvtpk(p_[12], p_[13]), y3_ = cvtpk(p_[14], p_[15]);             \
    plswap(x2_, y2_);                                                         \
    plswap(x3_, y3_);                                                         \
    u32x4 f1w_ = {x2_, x3_, y2_, y3_};                                        \
    s16x8 pf0_ = __builtin_bit_cast(s16x8, f0w_);                             \
    s16x8 pf1_ = __builtin_bit_cast(s16x8, f1w_);                             \
    __builtin_amdgcn_s_setprio(1);                                            \
    oL = mfma_32x32x16(VC[0], pf0_, oL);                                      \
    oH = mfma_32x32x16(VC[1], pf0_, oH);                                      \
    oL = mfma_32x32x16(VC[2], pf1_, oL);                                      \
    oH = mfma_32x32x16(VC[3], pf1_, oH);                                      \
    __builtin_amdgcn_s_setprio(0);                                            \
  } while (0)

#define OSTRIDE 68  // f32 row stride in LDS (bank-friendly, 16B-aligned)

__global__ __launch_bounds__(256, 3) void attn_fwd_k(
    const u16* __restrict__ Qp, const u16* __restrict__ Kp,
    const u16* __restrict__ Vp, u16* __restrict__ Y) {
  __shared__ float Ob[4 * 32 * OSTRIDE];   // 34816 B
  __shared__ float Ml[4 * 32 * 2];         // 1024 B
  int tid = threadIdx.x, lane = tid & 63, w = tid >> 6;
  int ql = lane & 31, h = lane >> 5;
  int bh = blockIdx.x & 31;
  int jt = 63 - (blockIdx.x >> 5);   // long tiles first
  int q0 = jt * 32;
  int b2 = bh >> 4, head = bh & 15;
  int n = jt + 1;
  int lo = (w * n) >> 2, hi = ((w + 1) * n) >> 2;  // this wave's KV range

  s16x8 qf[4];
#pragma unroll
  for (int ks = 0; ks < 4; ++ks)
    qf[ks] = *(const s16x8*)(Qp + (((u64)bh * 8 + ks * 2 + h) * T_ + q0 + ql) * 8);

  const u16* kp[4];
#pragma unroll
  for (int ks = 0; ks < 4; ++ks)
    kp[ks] = Kp + (((u64)bh * 8 + ks * 2 + h) * T_ + ql) * 8;
  const u16* vpb = Vp + (((u64)bh * (T_ / 8) + h) * HD_ + ql) * 8;

  fx16 oL = {}, oH = {};
  float m = -1e30f, l = 0.f;

  if (lo < hi) {
    s16x8 kA[4], vA[4], kB[4], vB[4];
    LOADK(kA, lo);
    LOADV(vA, lo);
    int kv = lo;
    for (; kv + 1 < hi; kv += 2) {
      LOADK(kB, kv + 1);
      LOADV(vB, kv + 1);
      ATTN_STEP(kA, vA, kv);
      if (kv + 2 < hi) {
        LOADK(kA, kv + 2);
        LOADV(vA, kv + 2);
      }
      ATTN_STEP(kB, vB, kv + 1);
    }
    if (kv < hi) ATTN_STEP(kA, vA, kv);
  }

  // combine per-half l partials once
  l = xhalf_sum(l);

  {
    float* ob = Ob + (w * 32 + ql) * OSTRIDE;
#pragma unroll
    for (int g = 0; g < 4; ++g) {
      fx4 a = {oL[4 * g], oL[4 * g + 1], oL[4 * g + 2], oL[4 * g + 3]};
      *(fx4*)(ob + 8 * g + 4 * h) = a;
      fx4 b = {oH[4 * g], oH[4 * g + 1], oH[4 * g + 2], oH[4 * g + 3]};
      *(fx4*)(ob + 32 + 8 * g + 4 * h) = b;
    }
    if (h == 0) {
      Ml[(w * 32 + ql) * 2] = m;
      Ml[(w * 32 + ql) * 2 + 1] = l;
    }
  }
  __syncthreads();

  {
    int q = tid >> 3, db = tid & 7;
    float mm0 = Ml[(0 * 32 + q) * 2], ll0 = Ml[(0 * 32 + q) * 2 + 1];
    float mm1 = Ml[(1 * 32 + q) * 2], ll1 = Ml[(1 * 32 + q) * 2 + 1];
    float mm2 = Ml[(2 * 32 + q) * 2], ll2 = Ml[(2 * 32 + q) * 2 + 1];
    float mm3 = Ml[(3 * 32 + q) * 2], ll3 = Ml[(3 * 32 + q) * 2 + 1];
    float mo = fmaxf(fmaxf(mm0, mm1), fmaxf(mm2, mm3));
    float w0 = exp2f(mm0 - mo), w1 = exp2f(mm1 - mo);
    float w2 = exp2f(mm2 - mo), w3 = exp2f(mm3 - mo);
    float rl = 1.0f / (ll0 * w0 + ll1 * w1 + ll2 * w2 + ll3 * w3);
    w0 *= rl; w1 *= rl; w2 *= rl; w3 *= rl;
    const float* ob = Ob + q * OSTRIDE + db * 8;
    fx4 aa = {}, bb = {};
#pragma unroll
    for (int i = 0; i < 4; ++i) {
      float wi = (i == 0) ? w0 : (i == 1) ? w1 : (i == 2) ? w2 : w3;
      fx4 pa = *(const fx4*)(ob + i * 32 * OSTRIDE);
      fx4 pb = *(const fx4*)(ob + i * 32 * OSTRIDE + 4);
      aa += wi * pa;
      bb += wi * pb;
    }
    u32x4 ow;
    ow[0] = cvtpk(aa[0], aa[1]);
    ow[1] = cvtpk(aa[2], aa[3]);
    ow[2] = cvtpk(bb[0], bb[1]);
    ow[3] = cvtpk(bb[2], bb[3]);
    int t = q0 + q;
    *(u32x4*)(Y + ((u64)(b2 * T_ + t)) * C_ + head * HD_ + db * 8) = ow;
  }
}

// ---------- launcher ----------
extern "C" void kernel_launch(void* const* d_in, const int* in_sizes, int n_in,
                              void* d_out, int out_size, void* d_ws, size_t ws_size,
                              hipStream_t stream) {
  (void)in_sizes; (void)n_in; (void)out_size; (void)ws_size;
  const float* x = (const float*)d_in[0];
  const float* w_attn = (const float*)d_in[1];
  const float* w_proj = (const float*)d_in[2];
  float* out = (float*)d_out;

  u16* xb = (u16*)d_ws;                       // [4096][1024] bf16 (reused as Y)
  u16* waT = xb + (u64)M_ * C_;               // [3072][1024]
  u16* wpT = waT + (u64)3 * C_ * C_;          // [1024][1024]
  u16* Qp = wpT + (u64)C_ * C_;               // [32][8][2048][8]
  u16* Kp = Qp + (u64)BH_ * T_ * HD_;
  u16* Vp = Kp + (u64)BH_ * T_ * HD_;         // [32][256][64][8]
  float* ct = (float*)(Vp + (u64)BH_ * T_ * HD_);
  float* st = ct + T_ * 32;
  u16* yb = xb;                               // reuse xb after GEMM1

  prep_k<<<3328, 256, 0, stream>>>(x, w_attn, w_proj, xb, waT, wpT, ct, st);

  gemm1_k<<<dim3(24, 32), 256, 0, stream>>>(xb, waT, Qp, Kp, Vp,
                                            ct, st, M_, 3 * C_, C_);

  attn_fwd_k<<<2048, 256, 0, stream>>>(Qp, Kp, Vp, yb);

  gemm2_nb<<<dim3(8, 32), 256, 0, stream>>>(yb, wpT, out, M_, C_, C_);
}